// Round 1
// baseline (1556.567 us; speedup 1.0000x reference)
//
#include <hip/hip_runtime.h>

typedef short short8 __attribute__((ext_vector_type(8)));
typedef float f32x4 __attribute__((ext_vector_type(4)));
typedef unsigned short u16;

static constexpr int BATCH = 2, S = 2048, H = 4096, NHEAD = 32, HDIM = 128;

__device__ __forceinline__ u16 f2b(float f) {
  union { float f; unsigned u; } v; v.f = f;
  return (u16)((v.u + 0x7fffu + ((v.u >> 16) & 1u)) >> 16);
}
__device__ __forceinline__ float b2f(u16 h) {
  union { unsigned u; float f; } v; v.u = ((unsigned)h) << 16;
  return v.f;
}

__device__ __forceinline__ void gl16(const u16* g, u16* l) {
  __builtin_amdgcn_global_load_lds((__attribute__((address_space(1))) void*)g,
                                   (__attribute__((address_space(3))) void*)l,
                                   16, 0, 0);
}

// ---- f32 -> bf16 convert, 4 elems/thread, exact grid ----
__global__ __launch_bounds__(256) void cvt_bf16(const float* __restrict__ in,
                                                u16* __restrict__ out) {
  size_t i = ((size_t)blockIdx.x * 256 + threadIdx.x) * 4;
  float4 v = *(const float4*)(in + i);
  ushort4 o = { f2b(v.x), f2b(v.y), f2b(v.z), f2b(v.w) };
  *(ushort4*)(out + i) = o;
}

// ---- NT GEMM: C[M][N] = A[M][K] * B[N][K]^T (both K-contiguous bf16) ----
// m97 structure: 128x128 tile, BK=32, 4 waves (2x2), 4x4 16x16x32 mfma / wave.
template <bool F32OUT>
__global__ __launch_bounds__(256) void gemm_bt(const u16* __restrict__ A,
                                               const u16* __restrict__ B,
                                               void* __restrict__ C,
                                               int M, int N, int K) {
  __shared__ u16 As[128 * 32];
  __shared__ u16 Bs[128 * 32];
  const int nbn = N >> 7;
  const int bm = blockIdx.x / nbn, bn = blockIdx.x % nbn;
  const int tid = threadIdx.x, lane = tid & 63;
  const int w = tid >> 6, wr = w >> 1, wc = w & 1;
  const int hi = lane >> 4, lo = lane & 15;
  f32x4 acc[4][4] = {};
  const u16* Ag = A + (size_t)bm * 128 * K;
  const u16* Bg = B + (size_t)bn * 128 * K;
  // 512 16B chunks per tile, 2 per thread; chunk c -> row c>>2, col (c&3)*8
  const int c0 = tid, c1 = tid + 256;
  const u16* a0 = Ag + (size_t)(c0 >> 2) * K + (c0 & 3) * 8;
  const u16* a1 = Ag + (size_t)(c1 >> 2) * K + (c1 & 3) * 8;
  const u16* b0 = Bg + (size_t)(c0 >> 2) * K + (c0 & 3) * 8;
  const u16* b1 = Bg + (size_t)(c1 >> 2) * K + (c1 & 3) * 8;
  u16* la0 = &As[c0 * 8]; u16* la1 = &As[c1 * 8];
  u16* lb0 = &Bs[c0 * 8]; u16* lb1 = &Bs[c1 * 8];
  for (int kt = 0; kt < K; kt += 32) {
    __syncthreads();
    gl16(a0 + kt, la0); gl16(a1 + kt, la1);
    gl16(b0 + kt, lb0); gl16(b1 + kt, lb1);
    __syncthreads();  // compiler drains vmcnt before s_barrier
    short8 af[4], bf[4];
#pragma unroll
    for (int m = 0; m < 4; ++m)
      af[m] = *(const short8*)&As[(wr * 64 + m * 16 + lo) * 32 + hi * 8];
#pragma unroll
    for (int n = 0; n < 4; ++n)
      bf[n] = *(const short8*)&Bs[(wc * 64 + n * 16 + lo) * 32 + hi * 8];
#pragma unroll
    for (int m = 0; m < 4; ++m)
#pragma unroll
      for (int n = 0; n < 4; ++n)
        acc[m][n] = __builtin_amdgcn_mfma_f32_16x16x32_bf16(af[m], bf[n],
                                                            acc[m][n], 0, 0, 0);
  }
  // C/D layout: col = lane&15, row = (lane>>4)*4 + reg  [verified m89/m91]
  const int r0 = bm * 128 + wr * 64 + hi * 4;
  const int col0 = bn * 128 + wc * 64 + lo;
#pragma unroll
  for (int m = 0; m < 4; ++m)
#pragma unroll
    for (int n = 0; n < 4; ++n)
#pragma unroll
      for (int j = 0; j < 4; ++j) {
        size_t idx = (size_t)(r0 + m * 16 + j) * N + col0 + n * 16;
        if (F32OUT) ((float*)C)[idx] = acc[m][n][j];
        else        ((u16*)C)[idx]   = f2b(acc[m][n][j]);
      }
}

// ---- RoPE + scatter: qkv[b][s][12288] -> q_r,k_r [b][nh][s][hd] ----
__global__ __launch_bounds__(256) void rope_qk(const u16* __restrict__ qkv,
                                               const int* __restrict__ pos,
                                               u16* __restrict__ qr,
                                               u16* __restrict__ kr) {
  __shared__ float cs[64], sn[64];
  const int bs = blockIdx.x;
  const int b = bs >> 11, s = bs & 2047;
  const int tid = threadIdx.x;
  if (tid < 64) {
    float p = (float)pos[bs];
    float freq = __powf(10000.0f, -(float)tid * (1.0f / 64.0f));
    float a = p * freq;
    sn[tid] = sinf(a);   // accurate versions: angle up to ~2047 rad
    cs[tid] = cosf(a);
  }
  __syncthreads();
  const u16* src = qkv + (size_t)bs * 12288;
  for (int i = tid; i < 4096; i += 256) {
    int nh = i >> 7, hd = i & 127, f = hd & 63;
    float c = cs[f], sv = sn[f];
    int oth = (hd < 64) ? i + 64 : i - 64;
    size_t dst = ((size_t)(b * NHEAD + nh) * S + s) * HDIM + hd;
    float x = b2f(src[i]), xo = b2f(src[oth]);
    qr[dst] = f2b((hd < 64) ? (x * c - xo * sv) : (x * c + xo * sv));
    float xk = b2f(src[4096 + i]), xko = b2f(src[4096 + oth]);
    kr[dst] = f2b((hd < 64) ? (xk * c - xko * sv) : (xk * c + xko * sv));
  }
}

// ---- flash attention fwd, causal. 1 block = (b, h, 64 q-rows), 4 waves x 16 rows.
__global__ __launch_bounds__(256) void flash_fwd(const u16* __restrict__ q,
                                                 const u16* __restrict__ k,
                                                 const u16* __restrict__ qkv,
                                                 u16* __restrict__ o) {
  constexpr int KPAD = 136;  // 272B rows: 16B-aligned, 2-way bank (free)
  constexpr int VPAD = 80;   // 160B rows: 16B-aligned, 4-way bank
  constexpr int PPAD = 80;
  __shared__ u16 Ks[64 * KPAD];
  __shared__ u16 Vt[128 * VPAD];   // V transposed: Vt[d][kv]
  __shared__ u16 Ps[4][16 * PPAD]; // per-wave P tile
  const int nqt = S / 64;
  const int qt = blockIdx.x % nqt, bh = blockIdx.x / nqt;
  const int b = bh >> 5, nh = bh & 31;
  const int tid = threadIdx.x, lane = tid & 63, w = tid >> 6;
  const int hi = lane >> 4, lo = lane & 15;

  const u16* qg = q + ((size_t)bh * S + qt * 64 + w * 16) * HDIM;
  short8 qf[4];
#pragma unroll
  for (int ks = 0; ks < 4; ++ks)
    qf[ks] = *(const short8*)(qg + (size_t)lo * HDIM + ks * 32 + hi * 8);

  float m_i[4], l_i[4];
  f32x4 oacc[8] = {};
#pragma unroll
  for (int j = 0; j < 4; ++j) { m_i[j] = -1e30f; l_i[j] = 0.0f; }

  const u16* kg = k + (size_t)bh * S * HDIM;
  for (int kvt = 0; kvt <= qt; ++kvt) {
    __syncthreads();
#pragma unroll
    for (int i = 0; i < 4; ++i) {  // stage K row-major, V transposed
      int c = tid + i * 256;
      int r = c >> 4, c8 = (c & 15) * 8;
      uint4 kk = *(const uint4*)(kg + (size_t)(kvt * 64 + r) * HDIM + c8);
      *(uint4*)&Ks[r * KPAD + c8] = kk;
      uint4 vv = *(const uint4*)(qkv + (size_t)(b * S + kvt * 64 + r) * 12288
                                  + 8192 + nh * 128 + c8);
      const u16* pv = (const u16*)&vv;
#pragma unroll
      for (int j = 0; j < 8; ++j) Vt[(c8 + j) * VPAD + r] = pv[j];
    }
    __syncthreads();
    f32x4 sc[4] = {};
#pragma unroll
    for (int ks = 0; ks < 4; ++ks)
#pragma unroll
      for (int cb = 0; cb < 4; ++cb)
        sc[cb] = __builtin_amdgcn_mfma_f32_16x16x32_bf16(
            qf[ks],
            *(const short8*)&Ks[(cb * 16 + lo) * KPAD + ks * 32 + hi * 8],
            sc[cb], 0, 0, 0);
    const int qrow = qt * 64 + w * 16 + hi * 4;
    const bool diag = (kvt == qt);
#pragma unroll
    for (int cb = 0; cb < 4; ++cb) {
      const int kvc = kvt * 64 + cb * 16 + lo;
#pragma unroll
      for (int j = 0; j < 4; ++j) {
        float sv = sc[cb][j] * 0.08838834764831845f;  // 128^-0.5
        if (diag && kvc > qrow + j) sv = -1e30f;
        sc[cb][j] = sv;
      }
    }
    float rmax[4], rs[4];
#pragma unroll
    for (int j = 0; j < 4; ++j) {
      rmax[j] = fmaxf(fmaxf(sc[0][j], sc[1][j]), fmaxf(sc[2][j], sc[3][j]));
      for (int d = 8; d; d >>= 1) rmax[j] = fmaxf(rmax[j], __shfl_xor(rmax[j], d));
      float mn = fmaxf(m_i[j], rmax[j]);
      float sf = __expf(m_i[j] - mn);
      m_i[j] = mn; l_i[j] *= sf;
#pragma unroll
      for (int db = 0; db < 8; ++db) oacc[db][j] *= sf;
      rs[j] = 0.0f;
    }
#pragma unroll
    for (int cb = 0; cb < 4; ++cb)
#pragma unroll
      for (int j = 0; j < 4; ++j) {
        float p = __expf(sc[cb][j] - m_i[j]);
        sc[cb][j] = p; rs[j] += p;
      }
#pragma unroll
    for (int j = 0; j < 4; ++j) {
      for (int d = 8; d; d >>= 1) rs[j] += __shfl_xor(rs[j], d);
      l_i[j] += rs[j];
    }
    // P: C-layout -> LDS -> A-fragment layout
#pragma unroll
    for (int cb = 0; cb < 4; ++cb)
#pragma unroll
      for (int j = 0; j < 4; ++j)
        Ps[w][(hi * 4 + j) * PPAD + cb * 16 + lo] = f2b(sc[cb][j]);
    __syncthreads();
#pragma unroll
    for (int ks2 = 0; ks2 < 2; ++ks2) {
      short8 pf = *(const short8*)&Ps[w][lo * PPAD + ks2 * 32 + hi * 8];
#pragma unroll
      for (int db = 0; db < 8; ++db)
        oacc[db] = __builtin_amdgcn_mfma_f32_16x16x32_bf16(
            pf,
            *(const short8*)&Vt[(db * 16 + lo) * VPAD + ks2 * 32 + hi * 8],
            oacc[db], 0, 0, 0);
    }
  }
#pragma unroll
  for (int j = 0; j < 4; ++j) {
    float inv = 1.0f / l_i[j];
    int srow = qt * 64 + w * 16 + hi * 4 + j;
    size_t base = ((size_t)b * S + srow) * H + (size_t)nh * HDIM + lo;
#pragma unroll
    for (int db = 0; db < 8; ++db)
      o[base + db * 16] = f2b(oacc[db][j] * inv);
  }
}

extern "C" void kernel_launch(void* const* d_in, const int* in_sizes, int n_in,
                              void* d_out, int out_size, void* d_ws, size_t ws_size,
                              hipStream_t stream) {
  const int* pos = (const int*)d_in[0];
  const float* hs = (const float*)d_in[1];
  const float* wpack = (const float*)d_in[2];
  const float* wo = (const float*)d_in[3];
  float* out = (float*)d_out;
  char* ws = (char*)d_ws;
  // ws layout (bytes), total 369,098,752:
  u16* hs_b    = (u16*)(ws + 0UL);          //  32 MiB: hidden bf16 [4096][4096]
  u16* wpack_b = (u16*)(ws + 33554432UL);   //  96 MiB: w_pack bf16 [12288][4096]
  u16* wo_b    = (u16*)(ws + 134217728UL);  //  32 MiB: w_o bf16 [4096][4096]
  u16* qkv_b   = (u16*)(ws + 167772160UL);  //  96 MiB: qkv bf16 [4096][12288]
  u16* q_r     = (u16*)(ws + 268435456UL);  //  32 MiB: q roped [B][NH][S][HD]
  u16* k_r     = (u16*)(ws + 301989888UL);  //  32 MiB: k roped
  u16* attn_b  = (u16*)(ws + 335544320UL);  //  32 MiB: attn out bf16 [4096][4096]

  cvt_bf16<<<16384, 256, 0, stream>>>(hs, hs_b);
  cvt_bf16<<<49152, 256, 0, stream>>>(wpack, wpack_b);
  cvt_bf16<<<16384, 256, 0, stream>>>(wo, wo_b);
  gemm_bt<false><<<32 * 96, 256, 0, stream>>>(hs_b, wpack_b, qkv_b, 4096, 12288, 4096);
  rope_qk<<<4096, 256, 0, stream>>>(qkv_b, pos, q_r, k_r);
  flash_fwd<<<64 * 32, 256, 0, stream>>>(q_r, k_r, qkv_b, attn_b);
  gemm_bt<true><<<32 * 32, 256, 0, stream>>>(attn_b, wo_b, out, 4096, 4096, 4096);
}